// Round 5
// baseline (277.394 us; speedup 1.0000x reference)
//
#include <hip/hip_runtime.h>
#include <math.h>

#define B_   64
#define S_   197
#define D_   768
#define H_   12
#define HD_  64
#define M_   (B_ * S_)     // 12608
#define MPAD 12672         // 99*128
#define KE   224           // padded contraction length over s (7*32)
#define BH_  (B_ * H_)     // 768
#define WSZ  ((size_t)D_ * D_)   // 589824

typedef _Float16 half8_t __attribute__((ext_vector_type(8)));
typedef _Float16 half4_t __attribute__((ext_vector_type(4)));
typedef _Float16 half2_t __attribute__((ext_vector_type(2)));
typedef float floatx4 __attribute__((ext_vector_type(4)));

// async global->LDS DMA, 16B per lane; lptr must be wave-uniform (HW adds lane*16)
#define LDS_DMA16(gptr, lptr) \
  __builtin_amdgcn_global_load_lds((const __attribute__((address_space(1))) void*)(gptr), \
                                   (__attribute__((address_space(3))) void*)(lptr), 16, 0, 0)

// ---------------------------------------------------------------------------
// Fused prep: [0,9504) X->fp16 (zero-pad rows to MPAD); [9504,11808) weight
// transpose+convert (Wk,Wv,Wq -> Tcat, Wo -> To); [11808,11810) E_k/E_v ->
// EET rows [0,64)/[64,128) as [r][KE] fp16 (zero-padded s>=197) + esum[r].
// ---------------------------------------------------------------------------
__global__ __launch_bounds__(256) void prep_kernel(
    const float* __restrict__ X,
    const float* __restrict__ Wq, const float* __restrict__ Wk,
    const float* __restrict__ Wv, const float* __restrict__ Wo,
    const float* __restrict__ Ek, const float* __restrict__ Ev,
    _Float16* __restrict__ Xh,
    _Float16* __restrict__ Tcat, _Float16* __restrict__ To,
    _Float16* __restrict__ EET,
    float* __restrict__ esumK, float* __restrict__ esumV)
{
    __shared__ float tile[32][33];
    const int bid = blockIdx.x, tid = threadIdx.x;
    if (bid < 9504) {
        const int i4 = (bid * 256 + tid) * 4;
        float4 v = make_float4(0.f, 0.f, 0.f, 0.f);
        if (i4 < M_ * D_) v = *(const float4*)&X[i4];
        half4_t o = { (_Float16)v.x, (_Float16)v.y, (_Float16)v.z, (_Float16)v.w };
        *(half4_t*)&Xh[i4] = o;
        return;
    }
    int b2 = bid - 9504;
    if (b2 < 2304) {
        const int z = b2 / 576, rem = b2 % 576;
        const int bx = rem % 24, by = rem / 24;
        // z: 0->Wk, 1->Wv, 2->Wq (into Tcat), 3->Wo (into To)
        const float* W = (z == 0) ? Wk : (z == 1) ? Wv : (z == 2) ? Wq : Wo;
        _Float16* T = (z < 3) ? (Tcat + (size_t)z * WSZ) : To;
        const int n0 = bx * 32, k0 = by * 32;
        const int r = tid >> 3, c4 = (tid & 7) * 4;
        *(float4*)&tile[r][c4] = *(const float4*)&W[(size_t)(k0 + r) * D_ + n0 + c4];
        __syncthreads();
        half4_t o = { (_Float16)tile[c4 + 0][r], (_Float16)tile[c4 + 1][r],
                      (_Float16)tile[c4 + 2][r], (_Float16)tile[c4 + 3][r] };
        *(half4_t*)&T[(size_t)(n0 + r) * D_ + k0 + c4] = o;
        return;
    }
    b2 -= 2304;   // 0 -> Ek, 1 -> Ev
    const float* E = b2 ? Ev : Ek;
    _Float16* ET = EET + (size_t)b2 * 64 * KE;
    float* es = b2 ? esumV : esumK;
    for (int i = tid; i < 64 * KE; i += 256) {
        const int rr = i / KE, s = i % KE;
        ET[i] = (_Float16)((s < S_) ? E[s * 64 + rr] : 0.f);
    }
    if (tid < 64) {
        float acc = 0.f;
        for (int s = 0; s < S_; ++s) acc += E[s * 64 + tid];
        es[tid] = acc;
    }
}

// ---------------------------------------------------------------------------
// Y[b] = E^T @ X_b  per batch: Ybuf rows [0,4096) = Y_k (b*64+r),
// rows [4096,8192) = Y_v.  One block per (b, 64-col tile). Contraction 224.
// A-frags direct from global EET; X slice staged s-major with +2 pad.
// ---------------------------------------------------------------------------
__global__ __launch_bounds__(256) void y_kernel(
    const _Float16* __restrict__ Xh, const _Float16* __restrict__ EET,
    _Float16* __restrict__ Ybuf)
{
    __shared__ _Float16 Xs[KE * 66];
    const int bid = blockIdx.x;
    const int b = bid / 12, n0 = (bid % 12) * 64;
    const int tid = threadIdx.x, w = tid >> 6, lane = tid & 63;
    const int l15 = lane & 15, quad = lane >> 4;

    #pragma unroll
    for (int i = 0; i < 7; ++i) {
        const int s = i * 32 + (tid >> 3);
        const int d0 = (tid & 7) * 8;
        // rows b*197+s for s in [197,224) read next-batch/zero-pad data;
        // they multiply EET's zero padding, so any finite value is fine.
        const half8_t v = *(const half8_t*)&Xh[(size_t)(b * S_ + s) * D_ + n0 + d0];
        #pragma unroll
        for (int jj = 0; jj < 4; ++jj) {
            half2_t t2 = { v[2 * jj], v[2 * jj + 1] };
            *(half2_t*)&Xs[s * 66 + d0 + 2 * jj] = t2;
        }
    }
    __syncthreads();

    floatx4 acc[2][4] = {};
    #pragma unroll
    for (int k7 = 0; k7 < 7; ++k7) {
        half8_t af[2];
        #pragma unroll
        for (int mi = 0; mi < 2; ++mi)
            af[mi] = *(const half8_t*)&EET[(w * 32 + mi * 16 + l15) * KE + k7 * 32 + quad * 8];
        #pragma unroll
        for (int ni = 0; ni < 4; ++ni) {
            const int sb = k7 * 32 + quad * 8;
            half8_t bf;
            #pragma unroll
            for (int jj = 0; jj < 8; ++jj) bf[jj] = Xs[(sb + jj) * 66 + ni * 16 + l15];
            #pragma unroll
            for (int mi = 0; mi < 2; ++mi)
                acc[mi][ni] = __builtin_amdgcn_mfma_f32_16x16x32_f16(
                    af[mi], bf, acc[mi][ni], 0, 0, 0);
        }
    }

    #pragma unroll
    for (int mi = 0; mi < 2; ++mi)
        #pragma unroll
        for (int ni = 0; ni < 4; ++ni)
            #pragma unroll
            for (int i = 0; i < 4; ++i) {
                const int m_local = w * 32 + mi * 16 + quad * 4 + i;
                const int row = (m_local >> 6) * 4096 + b * 64 + (m_local & 63);
                Ybuf[(size_t)row * D_ + n0 + ni * 16 + l15] = (_Float16)acc[mi][ni][i];
            }
}

// ---------------------------------------------------------------------------
// Unified GEMM (128x128 tile, BK=32, XOR-swizzled LDS, XCD-aware mapping).
// phase 0 (1008 blocks): [0,624) Q = Xh@Wq^T+bq -> Qh fp16;
//   [624,1008) PKV: pk/pv halves = Ybuf@W^T + esum[r]*b[n] -> pk16 / pvT.
// phase 1 (624 blocks): out = CTX@Wo^T+bo -> fp32, guard M_.
// ---------------------------------------------------------------------------
union GemmSmem {
    _Float16 stage[2][128 * 32];   // [0]=A, [1]=B
    _Float16 ct[4][64 * 68];       // epilogue transpose, per-wave
};

__global__ __launch_bounds__(256) void gemm_kernel(
    const _Float16* __restrict__ Xh, const _Float16* __restrict__ Ybuf,
    const _Float16* __restrict__ Tcat, const _Float16* __restrict__ To,
    const float* __restrict__ bq, const float* __restrict__ bk,
    const float* __restrict__ bv, const float* __restrict__ bo,
    const float* __restrict__ esumK, const float* __restrict__ esumV,
    _Float16* __restrict__ Qh, _Float16* __restrict__ pk16,
    _Float16* __restrict__ pvT, float* __restrict__ O32, int phase)
{
    __shared__ GemmSmem sm;
    const int bid = blockIdx.x;
    const _Float16 *A, *W;
    const float *bias, *esum = nullptr;
    _Float16* O16 = nullptr;
    int m0, n_in, mode;          // mode: 0 fp16 row-major, 1 fp32 guarded, 2 pvT
    int guardM = 1 << 30;

    if (phase == 1) {
        const int xcd = bid & 7, t = bid >> 3;
        const int slot = t / 6, j = t - slot * 6;
        const int m_blk = slot * 8 + xcd;
        if (m_blk >= MPAD / 128) return;
        m0 = m_blk * 128; n_in = j * 128;
        A = Xh; W = To; bias = bo; mode = 1; guardM = M_;
    } else if (bid < 624) {
        const int xcd = bid & 7, t = bid >> 3;
        const int slot = t / 6, j = t - slot * 6;
        const int m_blk = slot * 8 + xcd;
        if (m_blk >= MPAD / 128) return;
        m0 = m_blk * 128; n_in = j * 128;
        A = Xh; W = Tcat + 2 * WSZ; bias = bq; O16 = Qh; mode = 0;
    } else {
        const int b2 = bid - 624;
        const int xcd = b2 & 7, t = b2 >> 3;    // t in [0,48)
        const int slot = t / 6, j = t - slot * 6;
        const int m_blk = slot * 8 + xcd;       // 0..63
        m0 = m_blk * 128; n_in = j * 128;
        const int vhalf = (m_blk >= 32);
        A = Ybuf; W = Tcat + (size_t)vhalf * WSZ;
        bias = vhalf ? bv : bk; esum = vhalf ? esumV : esumK;
        if (vhalf) { mode = 2; }
        else       { O16 = pk16; mode = 0; }
    }

    const int tid = threadIdx.x;
    const int w = tid >> 6, lane = tid & 63;
    const int fr = lane & 15, quad = lane >> 4;
    const int jrow = lane >> 2;
    const int csw = ((lane & 3) ^ ((lane >> 3) & 3)) * 8;   // swizzled src chunk
    const int ksw = (quad ^ ((fr >> 1) & 3)) * 8;           // swizzled read slot
    const int wm = (w >> 1) * 64, wn = (w & 1) * 64;

    floatx4 acc[4][4] = {};

    for (int k0 = 0; k0 < D_; k0 += 32) {
        #pragma unroll
        for (int jj = 0; jj < 2; ++jj) {
            const int r = w * 32 + jj * 16 + jrow;
            LDS_DMA16(&A[(size_t)(m0 + r) * D_ + k0 + csw],
                      &sm.stage[0][w * 1024 + jj * 512]);
            LDS_DMA16(&W[(size_t)(n_in + r) * D_ + k0 + csw],
                      &sm.stage[1][w * 1024 + jj * 512]);
        }
        __syncthreads();
        half8_t af[4], bf[4];
        #pragma unroll
        for (int i = 0; i < 4; ++i) {
            af[i] = *(const half8_t*)&sm.stage[0][(wm + i * 16 + fr) * 32 + ksw];
            bf[i] = *(const half8_t*)&sm.stage[1][(wn + i * 16 + fr) * 32 + ksw];
        }
        #pragma unroll
        for (int mi = 0; mi < 4; ++mi)
            #pragma unroll
            for (int ni = 0; ni < 4; ++ni)
                acc[mi][ni] = __builtin_amdgcn_mfma_f32_16x16x32_f16(
                    af[mi], bf[ni], acc[mi][ni], 0, 0, 0);
        __syncthreads();
    }

    float bval[4];
    #pragma unroll
    for (int ni = 0; ni < 4; ++ni)
        bval[ni] = bias[n_in + wn + ni * 16 + fr];
    float rowf[4][4];
    #pragma unroll
    for (int mi = 0; mi < 4; ++mi)
        #pragma unroll
        for (int i = 0; i < 4; ++i)
            rowf[mi][i] = esum ? esum[(m0 + wm + mi * 16 + quad * 4 + i) & 63] : 1.f;

    if (mode == 1) {
        const int rq = quad * 4;
        #pragma unroll
        for (int ni = 0; ni < 4; ++ni) {
            const int n = n_in + wn + ni * 16 + fr;
            #pragma unroll
            for (int mi = 0; mi < 4; ++mi)
                #pragma unroll
                for (int i = 0; i < 4; ++i) {
                    const int m = m0 + wm + mi * 16 + rq + i;
                    if (m < guardM)
                        O32[(size_t)m * D_ + n] = acc[mi][ni][i] + bval[ni];
                }
        }
    } else if (mode == 2) {
        // pvT[bh][d][r]: row m -> (b,r), col n -> (h,d)
        #pragma unroll
        for (int ni = 0; ni < 4; ++ni) {
            const int n = n_in + wn + ni * 16 + fr;
            const int h = n >> 6, d = n & 63;
            #pragma unroll
            for (int mi = 0; mi < 4; ++mi)
                #pragma unroll
                for (int i = 0; i < 4; ++i) {
                    const int m = m0 + wm + mi * 16 + quad * 4 + i - 4096;
                    const int bb = m >> 6, r = m & 63;
                    pvT[((size_t)(bb * H_ + h)) * 4096 + d * 64 + r] =
                        (_Float16)(acc[mi][ni][i] + rowf[mi][i] * bval[ni]);
                }
        }
    } else {
        #pragma unroll
        for (int mi = 0; mi < 4; ++mi)
            #pragma unroll
            for (int ni = 0; ni < 4; ++ni)
                #pragma unroll
                for (int i = 0; i < 4; ++i)
                    sm.ct[w][(mi * 16 + quad * 4 + i) * 68 + ni * 16 + fr] =
                        (_Float16)(acc[mi][ni][i] + rowf[mi][i] * bval[ni]);
        #pragma unroll
        for (int pass = 0; pass < 8; ++pass) {
            const int rr = pass * 8 + (lane >> 3);
            const int cc = (lane & 7) * 8;
            const half8_t v = *(const half8_t*)&sm.ct[w][rr * 68 + cc];
            *(half8_t*)&O16[(size_t)(m0 + wm + rr) * D_ + n_in + wn + cc] = v;
        }
    }
}

// ---------------------------------------------------------------------------
// MFMA attention: one block per (b,h), barrier-free. pk rows strided 768 in
// pk16 (GEMM output layout); pvT compact [bh][d][r]. P round-trips a
// wave-private LDS band.
// ---------------------------------------------------------------------------
__global__ __launch_bounds__(256) void attn_kernel(
    const _Float16* __restrict__ Qh, const _Float16* __restrict__ pk16,
    const _Float16* __restrict__ pvT, _Float16* __restrict__ CTXh)
{
    __shared__ _Float16 P[64 * 80];
    const int bh = blockIdx.x, b = bh / H_, h = bh % H_;
    const int tid = threadIdx.x, w = tid >> 6, lane = tid & 63;
    const int l15 = lane & 15, quad = lane >> 4;
    const _Float16* pkB = pk16 + (size_t)(b * 64) * D_ + h * 64;
    const _Float16* pvB = pvT + (size_t)bh * 4096;
    const size_t qbase = (size_t)(b * S_) * D_ + h * HD_;

    half8_t bkf[4][2], bvf[4][2];
    #pragma unroll
    for (int ni = 0; ni < 4; ++ni)
        #pragma unroll
        for (int kk = 0; kk < 2; ++kk) {
            bkf[ni][kk] = *(const half8_t*)&pkB[(size_t)(ni * 16 + l15) * D_ + kk * 32 + quad * 8];
            bvf[ni][kk] = *(const half8_t*)&pvB[(ni * 16 + l15) * 64 + kk * 32 + quad * 8];
        }

    for (int t = w; t < 13; t += 4) {
        const int srow = t * 16;
        floatx4 acc[4] = {};
        #pragma unroll
        for (int kk = 0; kk < 2; ++kk) {
            const half8_t aq = *(const half8_t*)
                &Qh[qbase + (size_t)(srow + l15) * D_ + kk * 32 + quad * 8];
            #pragma unroll
            for (int ni = 0; ni < 4; ++ni)
                acc[ni] = __builtin_amdgcn_mfma_f32_16x16x32_f16(
                    aq, bkf[ni][kk], acc[ni], 0, 0, 0);
        }
        float p[4][4];
        #pragma unroll
        for (int i = 0; i < 4; ++i) {
            const float s0 = acc[0][i] * 0.125f, s1 = acc[1][i] * 0.125f;
            const float s2 = acc[2][i] * 0.125f, s3 = acc[3][i] * 0.125f;
            float mx = fmaxf(fmaxf(s0, s1), fmaxf(s2, s3));
            #pragma unroll
            for (int off = 1; off < 16; off <<= 1)
                mx = fmaxf(mx, __shfl_xor(mx, off, 64));
            const float e0 = __expf(s0 - mx), e1 = __expf(s1 - mx);
            const float e2 = __expf(s2 - mx), e3 = __expf(s3 - mx);
            float sme = e0 + e1 + e2 + e3;
            #pragma unroll
            for (int off = 1; off < 16; off <<= 1)
                sme += __shfl_xor(sme, off, 64);
            const float inv = 1.f / sme;
            p[0][i] = e0 * inv; p[1][i] = e1 * inv;
            p[2][i] = e2 * inv; p[3][i] = e3 * inv;
        }
        #pragma unroll
        for (int ni = 0; ni < 4; ++ni)
            #pragma unroll
            for (int i = 0; i < 4; ++i)
                P[(w * 16 + quad * 4 + i) * 80 + ni * 16 + l15] = (_Float16)p[ni][i];

        floatx4 accv[4] = {};
        #pragma unroll
        for (int kk = 0; kk < 2; ++kk) {
            const half8_t ap = *(const half8_t*)&P[(w * 16 + l15) * 80 + kk * 32 + quad * 8];
            #pragma unroll
            for (int ni = 0; ni < 4; ++ni)
                accv[ni] = __builtin_amdgcn_mfma_f32_16x16x32_f16(
                    ap, bvf[ni][kk], accv[ni], 0, 0, 0);
        }
        #pragma unroll
        for (int ni = 0; ni < 4; ++ni)
            #pragma unroll
            for (int i = 0; i < 4; ++i) {
                const int s = srow + quad * 4 + i;
                if (s < S_)
                    CTXh[qbase + (size_t)s * D_ + ni * 16 + l15] = (_Float16)accv[ni][i];
            }
    }
}

// ---------------------------------------------------------------------------
extern "C" void kernel_launch(void* const* d_in, const int* in_sizes, int n_in,
                              void* d_out, int out_size, void* d_ws, size_t ws_size,
                              hipStream_t stream) {
    const float* X   = (const float*)d_in[0];
    const float* Wq  = (const float*)d_in[1];
    const float* bq  = (const float*)d_in[2];
    const float* Wk  = (const float*)d_in[3];
    const float* bk  = (const float*)d_in[4];
    const float* Wv  = (const float*)d_in[5];
    const float* bv  = (const float*)d_in[6];
    const float* Wo  = (const float*)d_in[7];
    const float* bo  = (const float*)d_in[8];
    const float* E_k = (const float*)d_in[9];
    const float* E_v = (const float*)d_in[10];
    float* out = (float*)d_out;

    char* p = (char*)d_ws;
    _Float16* Xh   = (_Float16*)p; p += (size_t)MPAD * D_ * 2;   // reused as CTXh
    _Float16* Tcat = (_Float16*)p; p += (size_t)3 * WSZ * 2;
    _Float16* To   = (_Float16*)p; p += (size_t)WSZ * 2;
    _Float16* Qh   = (_Float16*)p; p += (size_t)MPAD * D_ * 2;
    _Float16* EET  = (_Float16*)p; p += (size_t)128 * KE * 2;
    float* esumK   = (float*)p;    p += 64 * sizeof(float);
    float* esumV   = (float*)p;    p += 64 * sizeof(float);
    _Float16* Ybuf = (_Float16*)p; p += (size_t)8192 * D_ * 2;
    _Float16* pk16 = (_Float16*)p; p += (size_t)4096 * D_ * 2;
    _Float16* pvT  = (_Float16*)p;

    prep_kernel<<<11810, 256, 0, stream>>>(X, Wq, Wk, Wv, Wo, E_k, E_v,
                                           Xh, Tcat, To, EET, esumK, esumV);
    y_kernel<<<768, 256, 0, stream>>>(Xh, EET, Ybuf);
    gemm_kernel<<<1008, 256, 0, stream>>>(Xh, Ybuf, Tcat, To,
                                          bq, bk, bv, bo, esumK, esumV,
                                          Qh, pk16, pvT, nullptr, 0);
    attn_kernel<<<BH_, 256, 0, stream>>>(Qh, pk16, pvT, Xh);
    gemm_kernel<<<624, 256, 0, stream>>>(Xh, Ybuf, Tcat, To,
                                         bq, bk, bv, bo, nullptr, nullptr,
                                         Qh, pk16, pvT, out, 1);
}

// Round 6
// 225.316 us; speedup vs baseline: 1.2311x; 1.2311x over previous
//
#include <hip/hip_runtime.h>
#include <math.h>

#define B_   64
#define S_   197
#define D_   768
#define H_   12
#define HD_  64
#define M_   (B_ * S_)     // 12608
#define MPAD 12672         // 99*128
#define KE   224           // padded contraction length over s (7*32)
#define BH_  (B_ * H_)     // 768
#define WSZ  ((size_t)D_ * D_)   // 589824

typedef _Float16 half8_t __attribute__((ext_vector_type(8)));
typedef _Float16 half4_t __attribute__((ext_vector_type(4)));
typedef _Float16 half2_t __attribute__((ext_vector_type(2)));
typedef float floatx4 __attribute__((ext_vector_type(4)));

// async global->LDS DMA, 16B per lane; lptr must be wave-uniform (HW adds lane*16)
#define LDS_DMA16(gptr, lptr) \
  __builtin_amdgcn_global_load_lds((const __attribute__((address_space(1))) void*)(gptr), \
                                   (__attribute__((address_space(3))) void*)(lptr), 16, 0, 0)

// ---------------------------------------------------------------------------
// Fused prep: [0,9504) X->fp16 (zero-pad rows to MPAD); [9504,11808) weight
// transpose+convert (Wk,Wv,Wq -> Tcat, Wo -> To); [11808,11810) E_k/E_v ->
// EET rows [0,64)/[64,128) as [r][KE] fp16 (zero-padded s>=197) + esum[r].
// ---------------------------------------------------------------------------
__global__ __launch_bounds__(256) void prep_kernel(
    const float* __restrict__ X,
    const float* __restrict__ Wq, const float* __restrict__ Wk,
    const float* __restrict__ Wv, const float* __restrict__ Wo,
    const float* __restrict__ Ek, const float* __restrict__ Ev,
    _Float16* __restrict__ Xh,
    _Float16* __restrict__ Tcat, _Float16* __restrict__ To,
    _Float16* __restrict__ EET,
    float* __restrict__ esumK, float* __restrict__ esumV)
{
    __shared__ float tile[32][33];
    const int bid = blockIdx.x, tid = threadIdx.x;
    if (bid < 9504) {
        const int i4 = (bid * 256 + tid) * 4;
        float4 v = make_float4(0.f, 0.f, 0.f, 0.f);
        if (i4 < M_ * D_) v = *(const float4*)&X[i4];
        half4_t o = { (_Float16)v.x, (_Float16)v.y, (_Float16)v.z, (_Float16)v.w };
        *(half4_t*)&Xh[i4] = o;
        return;
    }
    int b2 = bid - 9504;
    if (b2 < 2304) {
        const int z = b2 / 576, rem = b2 % 576;
        const int bx = rem % 24, by = rem / 24;
        // z: 0->Wk, 1->Wv, 2->Wq (into Tcat), 3->Wo (into To)
        const float* W = (z == 0) ? Wk : (z == 1) ? Wv : (z == 2) ? Wq : Wo;
        _Float16* T = (z < 3) ? (Tcat + (size_t)z * WSZ) : To;
        const int n0 = bx * 32, k0 = by * 32;
        const int r = tid >> 3, c4 = (tid & 7) * 4;
        *(float4*)&tile[r][c4] = *(const float4*)&W[(size_t)(k0 + r) * D_ + n0 + c4];
        __syncthreads();
        half4_t o = { (_Float16)tile[c4 + 0][r], (_Float16)tile[c4 + 1][r],
                      (_Float16)tile[c4 + 2][r], (_Float16)tile[c4 + 3][r] };
        *(half4_t*)&T[(size_t)(n0 + r) * D_ + k0 + c4] = o;
        return;
    }
    b2 -= 2304;   // 0 -> Ek, 1 -> Ev
    const float* E = b2 ? Ev : Ek;
    _Float16* ET = EET + (size_t)b2 * 64 * KE;
    float* es = b2 ? esumV : esumK;
    for (int i = tid; i < 64 * KE; i += 256) {
        const int rr = i / KE, s = i % KE;
        ET[i] = (_Float16)((s < S_) ? E[s * 64 + rr] : 0.f);
    }
    if (tid < 64) {
        float acc = 0.f;
        for (int s = 0; s < S_; ++s) acc += E[s * 64 + tid];
        es[tid] = acc;
    }
}

// ---------------------------------------------------------------------------
// Y[b] = E^T @ X_b per batch: Ybuf rows [0,4096) = Y_k (b*64+r),
// rows [4096,8192) = Y_v.  One block per (b, 64-col tile).
// ---------------------------------------------------------------------------
__global__ __launch_bounds__(256) void y_kernel(
    const _Float16* __restrict__ Xh, const _Float16* __restrict__ EET,
    _Float16* __restrict__ Ybuf)
{
    __shared__ _Float16 Xs[KE * 66];
    const int bid = blockIdx.x;
    const int b = bid / 12, n0 = (bid % 12) * 64;
    const int tid = threadIdx.x, w = tid >> 6, lane = tid & 63;
    const int l15 = lane & 15, quad = lane >> 4;

    #pragma unroll
    for (int i = 0; i < 7; ++i) {
        const int s = i * 32 + (tid >> 3);
        const int d0 = (tid & 7) * 8;
        // rows b*197+s for s in [197,224) multiply EET's zero padding
        const half8_t v = *(const half8_t*)&Xh[(size_t)(b * S_ + s) * D_ + n0 + d0];
        #pragma unroll
        for (int jj = 0; jj < 4; ++jj) {
            half2_t t2 = { v[2 * jj], v[2 * jj + 1] };
            *(half2_t*)&Xs[s * 66 + d0 + 2 * jj] = t2;
        }
    }
    __syncthreads();

    floatx4 acc[2][4] = {};
    #pragma unroll
    for (int k7 = 0; k7 < 7; ++k7) {
        half8_t af[2];
        #pragma unroll
        for (int mi = 0; mi < 2; ++mi)
            af[mi] = *(const half8_t*)&EET[(w * 32 + mi * 16 + l15) * KE + k7 * 32 + quad * 8];
        #pragma unroll
        for (int ni = 0; ni < 4; ++ni) {
            const int sb = k7 * 32 + quad * 8;
            half8_t bf;
            #pragma unroll
            for (int jj = 0; jj < 8; ++jj) bf[jj] = Xs[(sb + jj) * 66 + ni * 16 + l15];
            #pragma unroll
            for (int mi = 0; mi < 2; ++mi)
                acc[mi][ni] = __builtin_amdgcn_mfma_f32_16x16x32_f16(
                    af[mi], bf, acc[mi][ni], 0, 0, 0);
        }
    }

    #pragma unroll
    for (int mi = 0; mi < 2; ++mi)
        #pragma unroll
        for (int ni = 0; ni < 4; ++ni)
            #pragma unroll
            for (int i = 0; i < 4; ++i) {
                const int m_local = w * 32 + mi * 16 + quad * 4 + i;
                const int row = (m_local >> 6) * 4096 + b * 64 + (m_local & 63);
                Ybuf[(size_t)row * D_ + n0 + ni * 16 + l15] = (_Float16)acc[mi][ni][i];
            }
}

// ---------------------------------------------------------------------------
// Specialized GEMM (128x128 tile, BK=32, XOR-swizzled LDS, XCD-aware map).
// MODE 0 (624 blk): Qh = Xh@Wq^T+bq, fp16 transpose epilogue.
// MODE 1 (384 blk): m_blk<32: pk16 = Yk@Wk^T + esumK[r]*bk[n] (fp16 rows);
//                   m_blk>=32: pvT[bh][d][r] = Yv@Wv^T + esumV[r]*bv[n].
// MODE 2 (624 blk): out = CTX@Wo^T+bo, fp32 direct, guard M_.
// ---------------------------------------------------------------------------
union GemmSmem {
    _Float16 stage[2][128 * 32];   // [0]=A, [1]=B
    _Float16 ct[4][64 * 68];       // epilogue transpose, per-wave
};

template<int MODE>
__global__ __launch_bounds__(256) void gemm_t(
    const _Float16* __restrict__ A,
    const _Float16* __restrict__ W0, const _Float16* __restrict__ W1,
    const float* __restrict__ b0, const float* __restrict__ b1,
    const float* __restrict__ es0, const float* __restrict__ es1,
    _Float16* __restrict__ O16a, _Float16* __restrict__ pvT,
    float* __restrict__ O32)
{
    __shared__ GemmSmem sm;
    const int xcd = blockIdx.x & 7, t = blockIdx.x >> 3;
    const int slot = t / 6, j = t - slot * 6;
    const int m_blk = slot * 8 + xcd;
    if (MODE != 1 && m_blk >= MPAD / 128) return;
    const int m0 = m_blk * 128, n0 = j * 128;
    const bool vhalf = (MODE == 1) && (m_blk >= 32);
    const _Float16* W = vhalf ? W1 : W0;
    const float* bias = vhalf ? b1 : b0;
    const float* esum = vhalf ? es1 : es0;

    const int tid = threadIdx.x;
    const int w = tid >> 6, lane = tid & 63;
    const int fr = lane & 15, quad = lane >> 4;
    const int jrow = lane >> 2;
    const int csw = ((lane & 3) ^ ((lane >> 3) & 3)) * 8;   // swizzled src chunk
    const int ksw = (quad ^ ((fr >> 1) & 3)) * 8;           // swizzled read slot
    const int wm = (w >> 1) * 64, wn = (w & 1) * 64;

    floatx4 acc[4][4] = {};

    for (int k0 = 0; k0 < D_; k0 += 32) {
        #pragma unroll
        for (int jj = 0; jj < 2; ++jj) {
            const int r = w * 32 + jj * 16 + jrow;
            LDS_DMA16(&A[(size_t)(m0 + r) * D_ + k0 + csw],
                      &sm.stage[0][w * 1024 + jj * 512]);
            LDS_DMA16(&W[(size_t)(n0 + r) * D_ + k0 + csw],
                      &sm.stage[1][w * 1024 + jj * 512]);
        }
        __syncthreads();
        half8_t af[4], bf[4];
        #pragma unroll
        for (int i = 0; i < 4; ++i) {
            af[i] = *(const half8_t*)&sm.stage[0][(wm + i * 16 + fr) * 32 + ksw];
            bf[i] = *(const half8_t*)&sm.stage[1][(wn + i * 16 + fr) * 32 + ksw];
        }
        #pragma unroll
        for (int mi = 0; mi < 4; ++mi)
            #pragma unroll
            for (int ni = 0; ni < 4; ++ni)
                acc[mi][ni] = __builtin_amdgcn_mfma_f32_16x16x32_f16(
                    af[mi], bf[ni], acc[mi][ni], 0, 0, 0);
        __syncthreads();
    }

    float bval[4];
    #pragma unroll
    for (int ni = 0; ni < 4; ++ni)
        bval[ni] = bias[n0 + wn + ni * 16 + fr];

    if (MODE == 2) {
        const int rq = quad * 4;
        #pragma unroll
        for (int ni = 0; ni < 4; ++ni) {
            const int n = n0 + wn + ni * 16 + fr;
            #pragma unroll
            for (int mi = 0; mi < 4; ++mi)
                #pragma unroll
                for (int i = 0; i < 4; ++i) {
                    const int m = m0 + wm + mi * 16 + rq + i;
                    if (m < M_)
                        O32[(size_t)m * D_ + n] = acc[mi][ni][i] + bval[ni];
                }
        }
    } else if (MODE == 1 && vhalf) {
        // pvT[bh][d][r]; bb constant per wave, r = mi*16+quad*4+i
        const int bb = (m0 - 4096 + wm) >> 6;
        #pragma unroll
        for (int mi = 0; mi < 4; ++mi) {
            const float4 es4 = *(const float4*)&esum[mi * 16 + quad * 4];
            const float esv[4] = {es4.x, es4.y, es4.z, es4.w};
            #pragma unroll
            for (int ni = 0; ni < 4; ++ni) {
                const int n = n0 + wn + ni * 16 + fr;
                const int h = n >> 6, d = n & 63;
                #pragma unroll
                for (int i = 0; i < 4; ++i) {
                    const int r = mi * 16 + quad * 4 + i;
                    pvT[((size_t)(bb * H_ + h)) * 4096 + d * 64 + r] =
                        (_Float16)(acc[mi][ni][i] + esv[i] * bval[ni]);
                }
            }
        }
    } else {
        // Q (MODE 0) or pk (MODE 1 low half): LDS transpose + half8 row stores
        #pragma unroll
        for (int mi = 0; mi < 4; ++mi) {
            float esv[4] = {1.f, 1.f, 1.f, 1.f};
            if (MODE == 1) {
                const float4 es4 = *(const float4*)&esum[mi * 16 + quad * 4];
                esv[0] = es4.x; esv[1] = es4.y; esv[2] = es4.z; esv[3] = es4.w;
            }
            #pragma unroll
            for (int ni = 0; ni < 4; ++ni)
                #pragma unroll
                for (int i = 0; i < 4; ++i)
                    sm.ct[w][(mi * 16 + quad * 4 + i) * 68 + ni * 16 + fr] =
                        (_Float16)(acc[mi][ni][i] + esv[i] * bval[ni]);
        }
        #pragma unroll
        for (int pass = 0; pass < 8; ++pass) {
            const int rr = pass * 8 + (lane >> 3);
            const int cc = (lane & 7) * 8;
            const half8_t v = *(const half8_t*)&sm.ct[w][rr * 68 + cc];
            *(half8_t*)&O16a[(size_t)(m0 + wm + rr) * D_ + n0 + wn + cc] = v;
        }
    }
}

// ---------------------------------------------------------------------------
// MFMA attention: one block per (b,h), barrier-free. pk rows strided 768 in
// pk16 (GEMM output layout); pvT compact [bh][d][r]. P round-trips a
// wave-private LDS band.
// ---------------------------------------------------------------------------
__global__ __launch_bounds__(256) void attn_kernel(
    const _Float16* __restrict__ Qh, const _Float16* __restrict__ pk16,
    const _Float16* __restrict__ pvT, _Float16* __restrict__ CTXh)
{
    __shared__ _Float16 P[64 * 80];
    const int bh = blockIdx.x, b = bh / H_, h = bh % H_;
    const int tid = threadIdx.x, w = tid >> 6, lane = tid & 63;
    const int l15 = lane & 15, quad = lane >> 4;
    const _Float16* pkB = pk16 + (size_t)(b * 64) * D_ + h * 64;
    const _Float16* pvB = pvT + (size_t)bh * 4096;
    const size_t qbase = (size_t)(b * S_) * D_ + h * HD_;

    half8_t bkf[4][2], bvf[4][2];
    #pragma unroll
    for (int ni = 0; ni < 4; ++ni)
        #pragma unroll
        for (int kk = 0; kk < 2; ++kk) {
            bkf[ni][kk] = *(const half8_t*)&pkB[(size_t)(ni * 16 + l15) * D_ + kk * 32 + quad * 8];
            bvf[ni][kk] = *(const half8_t*)&pvB[(ni * 16 + l15) * 64 + kk * 32 + quad * 8];
        }

    for (int t = w; t < 13; t += 4) {
        const int srow = t * 16;
        floatx4 acc[4] = {};
        #pragma unroll
        for (int kk = 0; kk < 2; ++kk) {
            const half8_t aq = *(const half8_t*)
                &Qh[qbase + (size_t)(srow + l15) * D_ + kk * 32 + quad * 8];
            #pragma unroll
            for (int ni = 0; ni < 4; ++ni)
                acc[ni] = __builtin_amdgcn_mfma_f32_16x16x32_f16(
                    aq, bkf[ni][kk], acc[ni], 0, 0, 0);
        }
        float p[4][4];
        #pragma unroll
        for (int i = 0; i < 4; ++i) {
            const float s0 = acc[0][i] * 0.125f, s1 = acc[1][i] * 0.125f;
            const float s2 = acc[2][i] * 0.125f, s3 = acc[3][i] * 0.125f;
            float mx = fmaxf(fmaxf(s0, s1), fmaxf(s2, s3));
            #pragma unroll
            for (int off = 1; off < 16; off <<= 1)
                mx = fmaxf(mx, __shfl_xor(mx, off, 64));
            const float e0 = __expf(s0 - mx), e1 = __expf(s1 - mx);
            const float e2 = __expf(s2 - mx), e3 = __expf(s3 - mx);
            float sme = e0 + e1 + e2 + e3;
            #pragma unroll
            for (int off = 1; off < 16; off <<= 1)
                sme += __shfl_xor(sme, off, 64);
            const float inv = 1.f / sme;
            p[0][i] = e0 * inv; p[1][i] = e1 * inv;
            p[2][i] = e2 * inv; p[3][i] = e3 * inv;
        }
        #pragma unroll
        for (int ni = 0; ni < 4; ++ni)
            #pragma unroll
            for (int i = 0; i < 4; ++i)
                P[(w * 16 + quad * 4 + i) * 80 + ni * 16 + l15] = (_Float16)p[ni][i];

        floatx4 accv[4] = {};
        #pragma unroll
        for (int kk = 0; kk < 2; ++kk) {
            const half8_t ap = *(const half8_t*)&P[(w * 16 + l15) * 80 + kk * 32 + quad * 8];
            #pragma unroll
            for (int ni = 0; ni < 4; ++ni)
                accv[ni] = __builtin_amdgcn_mfma_f32_16x16x32_f16(
                    ap, bvf[ni][kk], accv[ni], 0, 0, 0);
        }
        #pragma unroll
        for (int ni = 0; ni < 4; ++ni)
            #pragma unroll
            for (int i = 0; i < 4; ++i) {
                const int s = srow + quad * 4 + i;
                if (s < S_)
                    CTXh[qbase + (size_t)s * D_ + ni * 16 + l15] = (_Float16)accv[ni][i];
            }
    }
}

// ---------------------------------------------------------------------------
extern "C" void kernel_launch(void* const* d_in, const int* in_sizes, int n_in,
                              void* d_out, int out_size, void* d_ws, size_t ws_size,
                              hipStream_t stream) {
    const float* X   = (const float*)d_in[0];
    const float* Wq  = (const float*)d_in[1];
    const float* bq  = (const float*)d_in[2];
    const float* Wk  = (const float*)d_in[3];
    const float* bk  = (const float*)d_in[4];
    const float* Wv  = (const float*)d_in[5];
    const float* bv  = (const float*)d_in[6];
    const float* Wo  = (const float*)d_in[7];
    const float* bo  = (const float*)d_in[8];
    const float* E_k = (const float*)d_in[9];
    const float* E_v = (const float*)d_in[10];
    float* out = (float*)d_out;

    char* p = (char*)d_ws;
    _Float16* Xh   = (_Float16*)p; p += (size_t)MPAD * D_ * 2;   // reused as CTXh
    _Float16* Tcat = (_Float16*)p; p += (size_t)3 * WSZ * 2;     // Wk,Wv,Wq
    _Float16* To   = (_Float16*)p; p += (size_t)WSZ * 2;
    _Float16* Qh   = (_Float16*)p; p += (size_t)MPAD * D_ * 2;
    _Float16* EET  = (_Float16*)p; p += (size_t)128 * KE * 2;
    float* esumK   = (float*)p;    p += 64 * sizeof(float);
    float* esumV   = (float*)p;    p += 64 * sizeof(float);
    _Float16* Ybuf = (_Float16*)p; p += (size_t)8192 * D_ * 2;
    _Float16* pk16 = (_Float16*)p; p += (size_t)4096 * D_ * 2;
    _Float16* pvT  = (_Float16*)p;

    prep_kernel<<<11810, 256, 0, stream>>>(X, Wq, Wk, Wv, Wo, E_k, E_v,
                                           Xh, Tcat, To, EET, esumK, esumV);
    y_kernel<<<768, 256, 0, stream>>>(Xh, EET, Ybuf);
    gemm_t<0><<<624, 256, 0, stream>>>(Xh, Tcat + 2 * WSZ, nullptr,
                                       bq, nullptr, nullptr, nullptr,
                                       Qh, nullptr, nullptr);
    gemm_t<1><<<384, 256, 0, stream>>>(Ybuf, Tcat, Tcat + WSZ,
                                       bk, bv, esumK, esumV,
                                       pk16, pvT, nullptr);
    attn_kernel<<<BH_, 256, 0, stream>>>(Qh, pk16, pvT, Xh);
    gemm_t<2><<<624, 256, 0, stream>>>(Xh, To, nullptr,
                                       bo, nullptr, nullptr, nullptr,
                                       nullptr, nullptr, out);
}